// Round 11
// baseline (164.794 us; speedup 1.0000x reference)
//
#include <hip/hip_runtime.h>
#include <hip/hip_cooperative_groups.h>
#include <stdint.h>

namespace cg = cooperative_groups;

// VectorQuantizer on MI355X (gfx950), round 23: single cooperative kernel.
// R22 post-mortem: fp16 3-term split gave exactly the predicted MFMA-pipe
// saving (-3.3us), confirming the main loop is ~9-11us of real work; the
// remaining structural cost is the two-dispatch pipeline: prep_m's serial
// run (~4-6us at 152 blocks), the inter-kernel drain, and the cold x
// prologue starting only at the 2nd launch. This round fuses prep+main
// into ONE kernel via hipLaunchCooperativeKernel (guide-blessed, harness-
// supported): phase A = 38913 prep tasks over 131072 threads (~30x more
// parallel), x prologue overlaps prep + sync skew, grid.sync(), then the
// R22-verified barrier-free fp16 loop byte-identical. Launch-error
// fallback to the proven R22 two-kernel path (no regression risk).

#define DDIM 64
#define KCODES 512

typedef _Float16 f16x8 __attribute__((ext_vector_type(8)));
typedef float f32x4 __attribute__((ext_vector_type(4)));

// ws layout (bytes): WB @0 (128 chunks x 1KB = 131072), wT @131072 (131072),
//                    wsq @262144 (2048) -> need 264192

__device__ __forceinline__ void split2(float f, _Float16& h1, _Float16& h2) {
  h1 = (_Float16)f;
  float r = f - (float)h1;   // exact (Sterbenz: RN(f) within factor 2 of f)
  h2 = (_Float16)r;          // residual beyond h2 ~ 2^-22 |f|
}

// ---------------- fused cooperative kernel ----------------

__global__ __launch_bounds__(256, 2)
void vq_fused(const float* __restrict__ x_in, const float* __restrict__ w,
              f16x8* __restrict__ wb, float* __restrict__ wT,
              float* __restrict__ wsq, float* __restrict__ out_q,
              float* __restrict__ out_idx, float* __restrict__ loss_out) {
  __shared__ unsigned long long sm_key[128];
  __shared__ float sm_xsq[128];
  __shared__ unsigned int sm_idx[128];
  __shared__ float sm_loss[128];

  const int t = threadIdx.x, b = blockIdx.x;  // 512 blocks, 128 pts each
  const int wv = t >> 6, L = t & 63, quad = L >> 4, col = L & 15;

  // ---- phase A: prep slice, 38913 tasks over 131072 threads ----
  const int gid = b * 256 + t;
  if (gid < 4096) {
    // w split -> B-fragment chunks (R22 prep formula, c = gid).
    // chunk G = ctg*4 + h*2 + s; element (G,Lp) = split s of
    // B[k=qp*8+32h+j][n=ctg*16+cp]  (R11 bench-verified fragment map)
    const int c = gid;
    const int ctg = c >> 7;
    const int h = (c >> 6) & 1;
    const int Lp = c & 63, qp = Lp >> 4, cp = Lp & 15;
    f16x8 v1, v2;
#pragma unroll
    for (int j = 0; j < 8; ++j) {
      float f = w[(qp * 8 + 32 * h + j) * KCODES + ctg * 16 + cp];
      _Float16 h1, h2; split2(f, h1, h2);
      v1[j] = h1; v2[j] = h2;
    }
    const int base = ctg * 4 + h * 2;
    wb[(base + 0) * 64 + Lp] = v1;
    wb[(base + 1) * 64 + Lp] = v2;
  } else if (gid < 36864) {
    // wT transpose
    int g = gid - 4096;
    int d = g >> 9, k = g & 511;
    wT[k * DDIM + d] = w[g];
  } else if (gid < 38912) {
    // wsq: 4 threads per code, 16 elems each, shfl tree (lane-aligned:
    // (36864 % 64) == 0)
    int i = gid - 36864;
    int k = i >> 2, p = i & 3;
    float s = 0.f;
#pragma unroll
    for (int dd = 0; dd < 16; ++dd) {
      float tv = w[(p * 16 + dd) * KCODES + k];
      s = fmaf(tv, tv, s);
    }
    s += __shfl_xor(s, 1, 64);
    s += __shfl_xor(s, 2, 64);
    if (p == 0) wsq[k] = s;
  } else if (gid == 38912) {
    *loss_out = 0.f;                          // d_out is poisoned each launch
  }

  // ---- x prologue: independent of prep output; overlaps other blocks'
  // prep work and the grid-sync arrival skew ----
  // a[as][s][h]; lane holds A[m=col][k=quad*8+32h+j] of point
  // pt = b*128 + (wv*2+as)*16 + col   (R11/R15 bench-verified A layout)
  f16x8 a[2][2][2];
#pragma unroll
  for (int as = 0; as < 2; ++as) {
    const float* xr =
        x_in + ((size_t)b * 128 + (wv * 2 + as) * 16 + col) * DDIM + quad * 8;
    float ssq = 0.f;
#pragma unroll
    for (int h = 0; h < 2; ++h) {
      float4 p0 = *(const float4*)(xr + 32 * h);
      float4 p1 = *(const float4*)(xr + 32 * h + 4);
      float f[8] = {p0.x, p0.y, p0.z, p0.w, p1.x, p1.y, p1.z, p1.w};
      f16x8 v1, v2;
#pragma unroll
      for (int j = 0; j < 8; ++j) {
        ssq = fmaf(f[j], f[j], ssq);
        _Float16 h1, h2; split2(f[j], h1, h2);
        v1[j] = h1; v2[j] = h2;
      }
      a[as][0][h] = v1; a[as][1][h] = v2;
    }
    // combine the 4 quads (lanes col, col+16, col+32, col+48 = same point)
    ssq += __shfl_xor(ssq, 16, 64);
    ssq += __shfl_xor(ssq, 32, 64);
    if (quad == 0) sm_xsq[wv * 32 + as * 16 + col] = ssq;  // fp32-exact
  }

  __threadfence();          // prep writes visible grid-wide
  cg::this_grid().sync();   // wb / wT / wsq / loss ready

  // ---- issue iteration-0 B prefetch ----
  f16x8 bb[2][4];
#pragma unroll
  for (int j = 0; j < 4; ++j) bb[0][j] = wb[j * 64 + L];

  float best[2][4];
  int bidx[2][4];
#pragma unroll
  for (int as = 0; as < 2; ++as)
#pragma unroll
    for (int r = 0; r < 4; ++r) { best[as][r] = 3.0e38f; bidx[as][r] = 0; }

  // ---- main loop: 32 free-running iterations (kk over 16-code tiles),
  // NO barriers. Iter kk consumes chunks 4kk..4kk+3 from bb[kk&1];
  // prefetches 4(kk+1).. into bb[~kk&1]. unroll 2 -> parity static.
#pragma unroll 2
  for (int kk = 0; kk < 32; ++kk) {
    const int cur = kk & 1, nxt = cur ^ 1;
    if (kk < 31) {
#pragma unroll
      for (int j = 0; j < 4; ++j)
        bb[nxt][j] = wb[(kk + 1) * 256 + j * 64 + L];
    }
    float wq = wsq[kk * 16 + col];           // 2KB L2-hot table

    // 12 MFMA: per as, dual-acc (h=0 -> aA, h=1 -> aB), 3-term fp16 split
    // {x1w1, x1w2, x2w1}; dropped x2w2 ~ 2^-22|x||w|.
    f32x4 aA0 = {0.f, 0.f, 0.f, 0.f}, aB0 = {0.f, 0.f, 0.f, 0.f};
    f32x4 aA1 = {0.f, 0.f, 0.f, 0.f}, aB1 = {0.f, 0.f, 0.f, 0.f};
    {
      f16x8 b0 = bb[cur][0], b1 = bb[cur][1];   // h=0: w1, w2
      aA0 = __builtin_amdgcn_mfma_f32_16x16x32_f16(a[0][0][0], b0, aA0, 0, 0, 0);
      aA1 = __builtin_amdgcn_mfma_f32_16x16x32_f16(a[1][0][0], b0, aA1, 0, 0, 0);
      aA0 = __builtin_amdgcn_mfma_f32_16x16x32_f16(a[0][0][0], b1, aA0, 0, 0, 0);
      aA1 = __builtin_amdgcn_mfma_f32_16x16x32_f16(a[1][0][0], b1, aA1, 0, 0, 0);
      aA0 = __builtin_amdgcn_mfma_f32_16x16x32_f16(a[0][1][0], b0, aA0, 0, 0, 0);
      aA1 = __builtin_amdgcn_mfma_f32_16x16x32_f16(a[1][1][0], b0, aA1, 0, 0, 0);
    }
    {
      f16x8 b2 = bb[cur][2], b3 = bb[cur][3];   // h=1: w1, w2
      aB0 = __builtin_amdgcn_mfma_f32_16x16x32_f16(a[0][0][1], b2, aB0, 0, 0, 0);
      aB1 = __builtin_amdgcn_mfma_f32_16x16x32_f16(a[1][0][1], b2, aB1, 0, 0, 0);
      aB0 = __builtin_amdgcn_mfma_f32_16x16x32_f16(a[0][0][1], b3, aB0, 0, 0, 0);
      aB1 = __builtin_amdgcn_mfma_f32_16x16x32_f16(a[1][0][1], b3, aB1, 0, 0, 0);
      aB0 = __builtin_amdgcn_mfma_f32_16x16x32_f16(a[0][1][1], b2, aB0, 0, 0, 0);
      aB1 = __builtin_amdgcn_mfma_f32_16x16x32_f16(a[1][1][1], b2, aB1, 0, 0, 0);
    }
    f32x4 acc0 = aA0 + aB0;
    f32x4 acc1 = aA1 + aB1;
    // dist + per-lane argmin; C layout: pt = quad*4 + r, code = col
    int code = kk * 16 + col;
#pragma unroll
    for (int r = 0; r < 4; ++r) {
      float d0 = fmaf(acc0[r], -2.0f, wq);
      if (d0 < best[0][r]) { best[0][r] = d0; bidx[0][r] = code; }
      float d1 = fmaf(acc1[r], -2.0f, wq);
      if (d1 < best[1][r]) { best[1][r] = d1; bidx[1][r] = code; }
    }
  }

  // ---- cross-lane reduce over the 16 cols; idx in low bits -> lowest idx ----
#pragma unroll
  for (int as = 0; as < 2; ++as) {
#pragma unroll
    for (int r = 0; r < 4; ++r) {
      unsigned int ub = __float_as_uint(best[as][r]);
      ub = (ub & 0x80000000u) ? ~ub : (ub | 0x80000000u);
      unsigned long long key = ((unsigned long long)ub << 32) |
                               (unsigned long long)(unsigned int)bidx[as][r];
#pragma unroll
      for (int off = 1; off < 16; off <<= 1) {
        unsigned long long o = __shfl_xor(key, off, 64);
        key = o < key ? o : key;
      }
      if (col == 0)
        sm_key[wv * 32 + as * 16 + quad * 4 + r] = key;
    }
  }
  __syncthreads();

  if (t < 128) {
    unsigned long long k = sm_key[t];
    unsigned int idx = (unsigned int)k;
    sm_idx[t] = idx;
    out_idx[(size_t)b * 128 + t] = (float)idx;
    unsigned int u = (unsigned int)(k >> 32);
    u = (u & 0x80000000u) ? (u & 0x7FFFFFFFu) : ~u;
    // ||x-q||^2 = ||x||^2 + (||q||^2 - 2 x.q), pre-scaled by 1.25/(N*D)
    sm_loss[t] = (__uint_as_float(u) + sm_xsq[t]) * (1.25f / 4194304.0f);
  }
  __syncthreads();

  // ---- fused epilogue: gather code rows, coalesced 128x64 out tile ----
  float4* dst = (float4*)(out_q + (size_t)b * 8192);
#pragma unroll
  for (int i = 0; i < 8; ++i) {
    int e4 = i * 256 + t;
    int p2 = e4 >> 4, d4 = e4 & 15;
    unsigned int idx = sm_idx[p2];                            // LDS broadcast
    dst[e4] = ((const float4*)(wT + (size_t)idx * DDIM))[d4]; // L2-hot
  }

  if (t < 64) {
    float s = sm_loss[t] + sm_loss[t + 64];
#pragma unroll
    for (int off = 32; off > 0; off >>= 1) s += __shfl_down(s, off);
    if (t == 0) atomicAdd(loss_out, s);       // 512 adds total
  }
}

// ---------------- two-kernel fallback (R22, bench-verified 93.07us) -------

__global__ void vq_prep_m(const float* __restrict__ w,
                          f16x8* __restrict__ wb,    // [128][64] chunks
                          float* __restrict__ wT, float* __restrict__ wsq,
                          float* __restrict__ loss_out) {
  const int b = blockIdx.x, t = threadIdx.x;
  if (b < 16) {
    const int c = b * 256 + t;                // 0..4095
    const int ctg = c >> 7;                   // 16-code tile 0..31
    const int h = (c >> 6) & 1;               // k-half
    const int L = c & 63, quad = L >> 4, col = L & 15;
    f16x8 v1, v2;
#pragma unroll
    for (int j = 0; j < 8; ++j) {
      float f = w[(quad * 8 + 32 * h + j) * KCODES + ctg * 16 + col];
      _Float16 h1, h2; split2(f, h1, h2);
      v1[j] = h1; v2[j] = h2;
    }
    const int base = ctg * 4 + h * 2;
    wb[(base + 0) * 64 + L] = v1;
    wb[(base + 1) * 64 + L] = v2;
  } else if (b < 144) {
    int g = (b - 16) * 256 + t;               // 0..32767 over D*K
    int d = g >> 9, k = g & 511;
    wT[k * DDIM + d] = w[g];
    if (g == 0) *loss_out = 0.f;
  } else {
    int i = (b - 144) * 256 + t;              // 0..2047
    int k = i >> 2, p = i & 3;
    float s = 0.f;
#pragma unroll
    for (int dd = 0; dd < 16; ++dd) {
      float tv = w[(p * 16 + dd) * KCODES + k];
      s = fmaf(tv, tv, s);
    }
    s += __shfl_xor(s, 1, 64);
    s += __shfl_xor(s, 2, 64);
    if (p == 0) wsq[k] = s;
  }
}

__global__ __launch_bounds__(256, 2)
void vq_mfma(const float* __restrict__ x_in, const f16x8* __restrict__ wb,
             const float* __restrict__ wsq, const float* __restrict__ wT,
             float* __restrict__ out_q, float* __restrict__ out_idx,
             float* __restrict__ loss_out) {
  __shared__ unsigned long long sm_key[128];
  __shared__ float sm_xsq[128];
  __shared__ unsigned int sm_idx[128];
  __shared__ float sm_loss[128];

  const int t = threadIdx.x, b = blockIdx.x;
  const int wv = t >> 6, L = t & 63, quad = L >> 4, col = L & 15;

  f16x8 bb[2][4];
#pragma unroll
  for (int j = 0; j < 4; ++j) bb[0][j] = wb[j * 64 + L];

  f16x8 a[2][2][2];
#pragma unroll
  for (int as = 0; as < 2; ++as) {
    const float* xr =
        x_in + ((size_t)b * 128 + (wv * 2 + as) * 16 + col) * DDIM + quad * 8;
    float ssq = 0.f;
#pragma unroll
    for (int h = 0; h < 2; ++h) {
      float4 p0 = *(const float4*)(xr + 32 * h);
      float4 p1 = *(const float4*)(xr + 32 * h + 4);
      float f[8] = {p0.x, p0.y, p0.z, p0.w, p1.x, p1.y, p1.z, p1.w};
      f16x8 v1, v2;
#pragma unroll
      for (int j = 0; j < 8; ++j) {
        ssq = fmaf(f[j], f[j], ssq);
        _Float16 h1, h2; split2(f[j], h1, h2);
        v1[j] = h1; v2[j] = h2;
      }
      a[as][0][h] = v1; a[as][1][h] = v2;
    }
    ssq += __shfl_xor(ssq, 16, 64);
    ssq += __shfl_xor(ssq, 32, 64);
    if (quad == 0) sm_xsq[wv * 32 + as * 16 + col] = ssq;
  }

  float best[2][4];
  int bidx[2][4];
#pragma unroll
  for (int as = 0; as < 2; ++as)
#pragma unroll
    for (int r = 0; r < 4; ++r) { best[as][r] = 3.0e38f; bidx[as][r] = 0; }

#pragma unroll 2
  for (int kk = 0; kk < 32; ++kk) {
    const int cur = kk & 1, nxt = cur ^ 1;
    if (kk < 31) {
#pragma unroll
      for (int j = 0; j < 4; ++j)
        bb[nxt][j] = wb[(kk + 1) * 256 + j * 64 + L];
    }
    float wq = wsq[kk * 16 + col];

    f32x4 aA0 = {0.f, 0.f, 0.f, 0.f}, aB0 = {0.f, 0.f, 0.f, 0.f};
    f32x4 aA1 = {0.f, 0.f, 0.f, 0.f}, aB1 = {0.f, 0.f, 0.f, 0.f};
    {
      f16x8 b0 = bb[cur][0], b1 = bb[cur][1];
      aA0 = __builtin_amdgcn_mfma_f32_16x16x32_f16(a[0][0][0], b0, aA0, 0, 0, 0);
      aA1 = __builtin_amdgcn_mfma_f32_16x16x32_f16(a[1][0][0], b0, aA1, 0, 0, 0);
      aA0 = __builtin_amdgcn_mfma_f32_16x16x32_f16(a[0][0][0], b1, aA0, 0, 0, 0);
      aA1 = __builtin_amdgcn_mfma_f32_16x16x32_f16(a[1][0][0], b1, aA1, 0, 0, 0);
      aA0 = __builtin_amdgcn_mfma_f32_16x16x32_f16(a[0][1][0], b0, aA0, 0, 0, 0);
      aA1 = __builtin_amdgcn_mfma_f32_16x16x32_f16(a[1][1][0], b0, aA1, 0, 0, 0);
    }
    {
      f16x8 b2 = bb[cur][2], b3 = bb[cur][3];
      aB0 = __builtin_amdgcn_mfma_f32_16x16x32_f16(a[0][0][1], b2, aB0, 0, 0, 0);
      aB1 = __builtin_amdgcn_mfma_f32_16x16x32_f16(a[1][0][1], b2, aB1, 0, 0, 0);
      aB0 = __builtin_amdgcn_mfma_f32_16x16x32_f16(a[0][0][1], b3, aB0, 0, 0, 0);
      aB1 = __builtin_amdgcn_mfma_f32_16x16x32_f16(a[1][0][1], b3, aB1, 0, 0, 0);
      aB0 = __builtin_amdgcn_mfma_f32_16x16x32_f16(a[0][1][1], b2, aB0, 0, 0, 0);
      aB1 = __builtin_amdgcn_mfma_f32_16x16x32_f16(a[1][1][1], b2, aB1, 0, 0, 0);
    }
    f32x4 acc0 = aA0 + aB0;
    f32x4 acc1 = aA1 + aB1;
    int code = kk * 16 + col;
#pragma unroll
    for (int r = 0; r < 4; ++r) {
      float d0 = fmaf(acc0[r], -2.0f, wq);
      if (d0 < best[0][r]) { best[0][r] = d0; bidx[0][r] = code; }
      float d1 = fmaf(acc1[r], -2.0f, wq);
      if (d1 < best[1][r]) { best[1][r] = d1; bidx[1][r] = code; }
    }
  }

#pragma unroll
  for (int as = 0; as < 2; ++as) {
#pragma unroll
    for (int r = 0; r < 4; ++r) {
      unsigned int ub = __float_as_uint(best[as][r]);
      ub = (ub & 0x80000000u) ? ~ub : (ub | 0x80000000u);
      unsigned long long key = ((unsigned long long)ub << 32) |
                               (unsigned long long)(unsigned int)bidx[as][r];
#pragma unroll
      for (int off = 1; off < 16; off <<= 1) {
        unsigned long long o = __shfl_xor(key, off, 64);
        key = o < key ? o : key;
      }
      if (col == 0)
        sm_key[wv * 32 + as * 16 + quad * 4 + r] = key;
    }
  }
  __syncthreads();

  if (t < 128) {
    unsigned long long k = sm_key[t];
    unsigned int idx = (unsigned int)k;
    sm_idx[t] = idx;
    out_idx[(size_t)b * 128 + t] = (float)idx;
    unsigned int u = (unsigned int)(k >> 32);
    u = (u & 0x80000000u) ? (u & 0x7FFFFFFFu) : ~u;
    sm_loss[t] = (__uint_as_float(u) + sm_xsq[t]) * (1.25f / 4194304.0f);
  }
  __syncthreads();

  float4* dst = (float4*)(out_q + (size_t)b * 8192);
#pragma unroll
  for (int i = 0; i < 8; ++i) {
    int e4 = i * 256 + t;
    int p2 = e4 >> 4, d4 = e4 & 15;
    unsigned int idx = sm_idx[p2];
    dst[e4] = ((const float4*)(wT + (size_t)idx * DDIM))[d4];
  }

  if (t < 64) {
    float s = sm_loss[t] + sm_loss[t + 64];
#pragma unroll
    for (int off = 32; off > 0; off >>= 1) s += __shfl_down(s, off);
    if (t == 0) atomicAdd(loss_out, s);
  }
}

// ---------------- fallback (R9 kernels, proven) ----------------

__global__ void vq_prep(const float* __restrict__ w, float* __restrict__ wT,
                        float* __restrict__ wsq, float* __restrict__ loss_out) {
  int g = blockIdx.x * 256 + threadIdx.x;
  int d = g >> 9, k = g & 511;
  wT[k * DDIM + d] = w[g];
  if (g < KCODES) {
    float s = 0.f;
    for (int dd = 0; dd < DDIM; ++dd) {
      float t = w[dd * KCODES + g];
      s = fmaf(t, t, s);
    }
    wsq[g] = s;
  }
  if (g == 0) *loss_out = 0.f;
}

__global__ __launch_bounds__(512, 8)
void vq_main(const float* __restrict__ x_in, const float* __restrict__ w,
             const float* __restrict__ wT, const float* __restrict__ wsq,
             float* __restrict__ out_q, float* __restrict__ out_idx,
             float* __restrict__ loss_out) {
  __shared__ float xs[DDIM][65];
  __shared__ unsigned long long sm_key[8][64];
  __shared__ unsigned int sm_idx[64];
  __shared__ float sm_sx[64];
  __shared__ float sm_loss[64];

  const int t = threadIdx.x;
  const int pb = blockIdx.x;
  const int wv = __builtin_amdgcn_readfirstlane(t >> 6);
  const int lane = t & 63;

  {
    const float4* src = (const float4*)(x_in + (size_t)pb * 4096);
#pragma unroll
    for (int i = 0; i < 2; ++i) {
      int e4 = i * 512 + t;
      float4 v = src[e4];
      int e = e4 << 2;
      int pt = e >> 6, d = e & 63;
      xs[d][pt] = v.x; xs[d + 1][pt] = v.y;
      xs[d + 2][pt] = v.z; xs[d + 3][pt] = v.w;
    }
  }
  __syncthreads();

  const int kbase = wv << 6;
  float best = 3.0e38f;
  int bidx = 0;
  float sx = 0.f;

#pragma unroll 1
  for (int kb = 0; kb < 2; ++kb) {
    const int k0 = kbase + (kb << 5);
    const float* wp = w + k0;
    float acc[32];
#pragma unroll
    for (int c = 0; c < 32; ++c) acc[c] = 0.f;
#pragma unroll 1
    for (int d8 = 0; d8 < 8; ++d8) {
      float xv[8];
#pragma unroll
      for (int dd = 0; dd < 8; ++dd) xv[dd] = xs[(d8 << 3) + dd][lane];
      if (wv == 0 && kb == 0) {
#pragma unroll
        for (int dd = 0; dd < 8; ++dd) sx = fmaf(xv[dd], xv[dd], sx);
      }
#pragma unroll
      for (int dd = 0; dd < 8; ++dd) {
        const float* wd = wp + (((d8 << 3) + dd) << 9);
#pragma unroll
        for (int c = 0; c < 32; ++c) acc[c] = fmaf(wd[c], xv[dd], acc[c]);
      }
    }
#pragma unroll
    for (int c = 0; c < 32; ++c) {
      float dist = fmaf(acc[c], -2.0f, wsq[k0 + c]);
      if (dist < best) { best = dist; bidx = k0 + c; }
    }
  }

  unsigned int ub = __float_as_uint(best);
  ub = (ub & 0x80000000u) ? ~ub : (ub | 0x80000000u);
  sm_key[wv][lane] =
      ((unsigned long long)ub << 32) | (unsigned long long)(unsigned int)bidx;
  if (wv == 0) sm_sx[lane] = sx;
  __syncthreads();

  if (t < 64) {
    unsigned long long k = sm_key[0][t];
#pragma unroll
    for (int wi = 1; wi < 8; ++wi) {
      unsigned long long k2 = sm_key[wi][t];
      k = k2 < k ? k2 : k;
    }
    unsigned int idx = (unsigned int)k;
    sm_idx[t] = idx;
    out_idx[((size_t)pb << 6) + t] = (float)idx;
    unsigned int u = (unsigned int)(k >> 32);
    u = (u & 0x80000000u) ? (u & 0x7FFFFFFFu) : ~u;
    sm_loss[t] = (__uint_as_float(u) + sm_sx[t]) * (1.25f / 4194304.0f);
  }
  __syncthreads();

  float4* dst = (float4*)(out_q + (size_t)pb * 4096);
#pragma unroll
  for (int i = 0; i < 2; ++i) {
    int e4 = i * 512 + t;
    int p2 = e4 >> 4, d4 = e4 & 15;
    unsigned int idx = sm_idx[p2];
    dst[e4] = ((const float4*)(wT + (size_t)idx * DDIM))[d4];
  }

  if (t < 64) {
    float s = sm_loss[t];
#pragma unroll
    for (int off = 32; off > 0; off >>= 1) s += __shfl_down(s, off);
    if (t == 0) atomicAdd(loss_out, s);
  }
}

extern "C" void kernel_launch(void* const* d_in, const int* in_sizes, int n_in,
                              void* d_out, int out_size, void* d_ws, size_t ws_size,
                              hipStream_t stream) {
  const float* x = (const float*)d_in[0];  // (64,32,32,64) fp32
  const float* w = (const float*)d_in[1];  // (64,512) fp32

  float* out_q = (float*)d_out;            // 4194304 floats
  float* out_idx = out_q + 4194304;        // 65536 floats (indices)
  float* loss_out = out_q + 4259840;       // 1 float

  char* ws = (char*)d_ws;
  if (ws_size >= 264192) {
    f16x8* wbp = (f16x8*)(ws);
    float* wT = (float*)(ws + 131072);
    float* wsq = (float*)(ws + 262144);
    void* args[] = {(void*)&x,     (void*)&w,       (void*)&wbp,
                    (void*)&wT,    (void*)&wsq,     (void*)&out_q,
                    (void*)&out_idx, (void*)&loss_out};
    hipError_t err = hipLaunchCooperativeKernel(
        (void*)vq_fused, dim3(512), dim3(256), args, 0, stream);
    if (err != hipSuccess) {
      // proven R22 two-kernel path (93.07us verified)
      vq_prep_m<<<152, 256, 0, stream>>>(w, wbp, wT, wsq, loss_out);
      vq_mfma<<<512, 256, 0, stream>>>(x, wbp, wsq, wT, out_q, out_idx,
                                       loss_out);
    }
  } else {
    float* wT = (float*)(ws);
    float* wsq = (float*)(ws + 131072);
    vq_prep<<<128, 256, 0, stream>>>(w, wT, wsq, loss_out);
    vq_main<<<1024, 512, 0, stream>>>(x, w, wT, wsq, out_q, out_idx,
                                      loss_out);
  }
}

// Round 12
// 92.814 us; speedup vs baseline: 1.7755x; 1.7755x over previous
//
#include <hip/hip_runtime.h>
#include <stdint.h>

// VectorQuantizer on MI355X (gfx950), round 24: R22 revert + coalesced
// wT transpose. R23 post-mortem: cooperative grid.sync() costs ~50us on
// gfx950 (8 non-coherent XCD L2s -> device-scope flush protocol; vq_fused
// alone 88-93us, MfmaUtil 5%) -- fusion abandoned. Base = R22 (93.07us
// bench-verified): fp16 3-term split, barrier-free global-B-stream loop.
// This round's ONLY delta: prep_m wT mapping was k=g&511 -> consecutive
// threads write stride-256B (16x write amplification, every 4B store its
// own 64B line). Now k=g>>6, d=g&63: writes contiguous (64 dwords/wave),
// reads strided but L2-absorbed (w = 128KB, lines shared across blocks).
// Everything else byte-identical to R22. Fragment maps R11-verified.

#define DDIM 64
#define KCODES 512

typedef _Float16 f16x8 __attribute__((ext_vector_type(8)));
typedef float f32x4 __attribute__((ext_vector_type(4)));

// ws layout (bytes): WB @0 (128 chunks x 1KB = 131072), wT @131072 (131072),
//                    wsq @262144 (2048) -> need 264192

__device__ __forceinline__ void split2(float f, _Float16& h1, _Float16& h2) {
  h1 = (_Float16)f;
  float r = f - (float)h1;   // exact (Sterbenz: RN(f) within factor 2 of f)
  h2 = (_Float16)r;          // residual beyond h2 ~ 2^-22 |f|
}

__global__ void vq_prep_m(const float* __restrict__ w,
                          f16x8* __restrict__ wb,    // [128][64] chunks
                          float* __restrict__ wT, float* __restrict__ wsq,
                          float* __restrict__ loss_out) {
  const int b = blockIdx.x, t = threadIdx.x;
  if (b < 16) {
    // ---- w split -> B-fragment chunks, fp16 layout ----
    // chunk G = ctg*4 + h*2 + s (ctg = 16-code tile 0..31, h = k-half,
    // s = split term). Element (G,L) = split s of
    // B[k=quad*8+32h+j][n=ctg*16+col]  (R11 bench-verified fragment map)
    const int c = b * 256 + t;                // 0..4095
    const int ctg = c >> 7;                   // 16-code tile 0..31
    const int h = (c >> 6) & 1;               // k-half
    const int L = c & 63, quad = L >> 4, col = L & 15;
    f16x8 v1, v2;
#pragma unroll
    for (int j = 0; j < 8; ++j) {
      float f = w[(quad * 8 + 32 * h + j) * KCODES + ctg * 16 + col];
      _Float16 h1, h2; split2(f, h1, h2);
      v1[j] = h1; v2[j] = h2;
    }
    const int base = ctg * 4 + h * 2;
    wb[(base + 0) * 64 + L] = v1;
    wb[(base + 1) * 64 + L] = v2;
  } else if (b < 144) {
    // ---- wT transpose (coalesced WRITES: consecutive t -> consecutive d,
    // wT[k*64+d] contiguous per wave; reads w[d*512+k] strided, L2-hot)
    // + loss zero ----
    int g = (b - 16) * 256 + t;               // 0..32767 over K*D
    int k = g >> 6, d = g & 63;
    wT[k * DDIM + d] = w[d * KCODES + k];
    if (g == 0) *loss_out = 0.f;              // d_out is poisoned each launch
  } else {
    // ---- wsq: 4 threads per code, 16 elems each, shfl tree ----
    int i = (b - 144) * 256 + t;              // 0..2047
    int k = i >> 2, p = i & 3;
    float s = 0.f;
#pragma unroll
    for (int dd = 0; dd < 16; ++dd) {
      float tv = w[(p * 16 + dd) * KCODES + k];
      s = fmaf(tv, tv, s);
    }
    s += __shfl_xor(s, 1, 64);
    s += __shfl_xor(s, 2, 64);
    if (p == 0) wsq[k] = s;
  }
}

__global__ __launch_bounds__(256, 2)
void vq_mfma(const float* __restrict__ x_in, const f16x8* __restrict__ wb,
             const float* __restrict__ wsq, const float* __restrict__ wT,
             float* __restrict__ out_q, float* __restrict__ out_idx,
             float* __restrict__ loss_out) {
  __shared__ unsigned long long sm_key[128];
  __shared__ float sm_xsq[128];
  __shared__ unsigned int sm_idx[128];
  __shared__ float sm_loss[128];

  const int t = threadIdx.x, b = blockIdx.x;  // 512 blocks, 128 pts each
  const int wv = t >> 6, L = t & 63, quad = L >> 4, col = L & 15;

  // ---- issue iteration-0 B prefetch FIRST (covers L2 latency under the
  // x prologue's loads + split VALU) ----
  f16x8 bb[2][4];
#pragma unroll
  for (int j = 0; j < 4; ++j) bb[0][j] = wb[j * 64 + L];

  // ---- load A-fragments straight from x, split2 in-register ----
  // a[as][s][h]; lane holds A[m=col][k=quad*8+32h+j] of point
  // pt = b*128 + (wv*2+as)*16 + col   (R11/R15 bench-verified A layout)
  f16x8 a[2][2][2];
#pragma unroll
  for (int as = 0; as < 2; ++as) {
    const float* xr =
        x_in + ((size_t)b * 128 + (wv * 2 + as) * 16 + col) * DDIM + quad * 8;
    float ssq = 0.f;
#pragma unroll
    for (int h = 0; h < 2; ++h) {
      float4 p0 = *(const float4*)(xr + 32 * h);
      float4 p1 = *(const float4*)(xr + 32 * h + 4);
      float f[8] = {p0.x, p0.y, p0.z, p0.w, p1.x, p1.y, p1.z, p1.w};
      f16x8 v1, v2;
#pragma unroll
      for (int j = 0; j < 8; ++j) {
        ssq = fmaf(f[j], f[j], ssq);
        _Float16 h1, h2; split2(f[j], h1, h2);
        v1[j] = h1; v2[j] = h2;
      }
      a[as][0][h] = v1; a[as][1][h] = v2;
    }
    // combine the 4 quads (lanes col, col+16, col+32, col+48 = same point)
    ssq += __shfl_xor(ssq, 16, 64);
    ssq += __shfl_xor(ssq, 32, 64);
    if (quad == 0) sm_xsq[wv * 32 + as * 16 + col] = ssq;  // fp32-exact
  }

  float best[2][4];
  int bidx[2][4];
#pragma unroll
  for (int as = 0; as < 2; ++as)
#pragma unroll
    for (int r = 0; r < 4; ++r) { best[as][r] = 3.0e38f; bidx[as][r] = 0; }

  // ---- main loop: 32 free-running iterations (kk over 16-code tiles),
  // NO barriers. Iter kk consumes chunks 4kk..4kk+3 from bb[kk&1];
  // prefetches 4(kk+1).. into bb[~kk&1]. unroll 2 -> parity static.
#pragma unroll 2
  for (int kk = 0; kk < 32; ++kk) {
    const int cur = kk & 1, nxt = cur ^ 1;
    if (kk < 31) {
#pragma unroll
      for (int j = 0; j < 4; ++j)
        bb[nxt][j] = wb[(kk + 1) * 256 + j * 64 + L];
    }
    float wq = wsq[kk * 16 + col];           // 2KB L2-hot table

    // 12 MFMA: per as, dual-acc (h=0 -> aA, h=1 -> aB), 3-term fp16 split
    // {x1w1, x1w2, x2w1}; dropped x2w2 ~ 2^-22|x||w|.
    f32x4 aA0 = {0.f, 0.f, 0.f, 0.f}, aB0 = {0.f, 0.f, 0.f, 0.f};
    f32x4 aA1 = {0.f, 0.f, 0.f, 0.f}, aB1 = {0.f, 0.f, 0.f, 0.f};
    {
      f16x8 b0 = bb[cur][0], b1 = bb[cur][1];   // h=0: w1, w2
      aA0 = __builtin_amdgcn_mfma_f32_16x16x32_f16(a[0][0][0], b0, aA0, 0, 0, 0);
      aA1 = __builtin_amdgcn_mfma_f32_16x16x32_f16(a[1][0][0], b0, aA1, 0, 0, 0);
      aA0 = __builtin_amdgcn_mfma_f32_16x16x32_f16(a[0][0][0], b1, aA0, 0, 0, 0);
      aA1 = __builtin_amdgcn_mfma_f32_16x16x32_f16(a[1][0][0], b1, aA1, 0, 0, 0);
      aA0 = __builtin_amdgcn_mfma_f32_16x16x32_f16(a[0][1][0], b0, aA0, 0, 0, 0);
      aA1 = __builtin_amdgcn_mfma_f32_16x16x32_f16(a[1][1][0], b0, aA1, 0, 0, 0);
    }
    {
      f16x8 b2 = bb[cur][2], b3 = bb[cur][3];   // h=1: w1, w2
      aB0 = __builtin_amdgcn_mfma_f32_16x16x32_f16(a[0][0][1], b2, aB0, 0, 0, 0);
      aB1 = __builtin_amdgcn_mfma_f32_16x16x32_f16(a[1][0][1], b2, aB1, 0, 0, 0);
      aB0 = __builtin_amdgcn_mfma_f32_16x16x32_f16(a[0][0][1], b3, aB0, 0, 0, 0);
      aB1 = __builtin_amdgcn_mfma_f32_16x16x32_f16(a[1][0][1], b3, aB1, 0, 0, 0);
      aB0 = __builtin_amdgcn_mfma_f32_16x16x32_f16(a[0][1][1], b2, aB0, 0, 0, 0);
      aB1 = __builtin_amdgcn_mfma_f32_16x16x32_f16(a[1][1][1], b2, aB1, 0, 0, 0);
    }
    f32x4 acc0 = aA0 + aB0;
    f32x4 acc1 = aA1 + aB1;
    // dist + per-lane argmin; C layout: pt = quad*4 + r, code = col
    int code = kk * 16 + col;
#pragma unroll
    for (int r = 0; r < 4; ++r) {
      float d0 = fmaf(acc0[r], -2.0f, wq);
      if (d0 < best[0][r]) { best[0][r] = d0; bidx[0][r] = code; }
      float d1 = fmaf(acc1[r], -2.0f, wq);
      if (d1 < best[1][r]) { best[1][r] = d1; bidx[1][r] = code; }
    }
  }

  // ---- cross-lane reduce over the 16 cols; idx in low bits -> lowest idx ----
#pragma unroll
  for (int as = 0; as < 2; ++as) {
#pragma unroll
    for (int r = 0; r < 4; ++r) {
      unsigned int ub = __float_as_uint(best[as][r]);
      ub = (ub & 0x80000000u) ? ~ub : (ub | 0x80000000u);
      unsigned long long key = ((unsigned long long)ub << 32) |
                               (unsigned long long)(unsigned int)bidx[as][r];
#pragma unroll
      for (int off = 1; off < 16; off <<= 1) {
        unsigned long long o = __shfl_xor(key, off, 64);
        key = o < key ? o : key;
      }
      if (col == 0)
        sm_key[wv * 32 + as * 16 + quad * 4 + r] = key;
    }
  }
  __syncthreads();

  if (t < 128) {
    unsigned long long k = sm_key[t];
    unsigned int idx = (unsigned int)k;
    sm_idx[t] = idx;
    out_idx[(size_t)b * 128 + t] = (float)idx;
    unsigned int u = (unsigned int)(k >> 32);
    u = (u & 0x80000000u) ? (u & 0x7FFFFFFFu) : ~u;
    // ||x-q||^2 = ||x||^2 + (||q||^2 - 2 x.q), pre-scaled by 1.25/(N*D)
    sm_loss[t] = (__uint_as_float(u) + sm_xsq[t]) * (1.25f / 4194304.0f);
  }
  __syncthreads();

  // ---- fused epilogue: gather code rows, coalesced 128x64 out tile ----
  float4* dst = (float4*)(out_q + (size_t)b * 8192);
#pragma unroll
  for (int i = 0; i < 8; ++i) {
    int e4 = i * 256 + t;
    int p2 = e4 >> 4, d4 = e4 & 15;
    unsigned int idx = sm_idx[p2];                            // LDS broadcast
    dst[e4] = ((const float4*)(wT + (size_t)idx * DDIM))[d4]; // L2-hot
  }

  if (t < 64) {
    float s = sm_loss[t] + sm_loss[t + 64];
#pragma unroll
    for (int off = 32; off > 0; off >>= 1) s += __shfl_down(s, off);
    if (t == 0) atomicAdd(loss_out, s);       // 512 adds total
  }
}

// ---------------- fallback (R9 kernels, proven) ----------------

__global__ void vq_prep(const float* __restrict__ w, float* __restrict__ wT,
                        float* __restrict__ wsq, float* __restrict__ loss_out) {
  int g = blockIdx.x * 256 + threadIdx.x;
  int d = g >> 9, k = g & 511;
  wT[k * DDIM + d] = w[g];
  if (g < KCODES) {
    float s = 0.f;
    for (int dd = 0; dd < DDIM; ++dd) {
      float t = w[dd * KCODES + g];
      s = fmaf(t, t, s);
    }
    wsq[g] = s;
  }
  if (g == 0) *loss_out = 0.f;
}

__global__ __launch_bounds__(512, 8)
void vq_main(const float* __restrict__ x_in, const float* __restrict__ w,
             const float* __restrict__ wT, const float* __restrict__ wsq,
             float* __restrict__ out_q, float* __restrict__ out_idx,
             float* __restrict__ loss_out) {
  __shared__ float xs[DDIM][65];
  __shared__ unsigned long long sm_key[8][64];
  __shared__ unsigned int sm_idx[64];
  __shared__ float sm_sx[64];
  __shared__ float sm_loss[64];

  const int t = threadIdx.x;
  const int pb = blockIdx.x;
  const int wv = __builtin_amdgcn_readfirstlane(t >> 6);
  const int lane = t & 63;

  {
    const float4* src = (const float4*)(x_in + (size_t)pb * 4096);
#pragma unroll
    for (int i = 0; i < 2; ++i) {
      int e4 = i * 512 + t;
      float4 v = src[e4];
      int e = e4 << 2;
      int pt = e >> 6, d = e & 63;
      xs[d][pt] = v.x; xs[d + 1][pt] = v.y;
      xs[d + 2][pt] = v.z; xs[d + 3][pt] = v.w;
    }
  }
  __syncthreads();

  const int kbase = wv << 6;
  float best = 3.0e38f;
  int bidx = 0;
  float sx = 0.f;

#pragma unroll 1
  for (int kb = 0; kb < 2; ++kb) {
    const int k0 = kbase + (kb << 5);
    const float* wp = w + k0;
    float acc[32];
#pragma unroll
    for (int c = 0; c < 32; ++c) acc[c] = 0.f;
#pragma unroll 1
    for (int d8 = 0; d8 < 8; ++d8) {
      float xv[8];
#pragma unroll
      for (int dd = 0; dd < 8; ++dd) xv[dd] = xs[(d8 << 3) + dd][lane];
      if (wv == 0 && kb == 0) {
#pragma unroll
        for (int dd = 0; dd < 8; ++dd) sx = fmaf(xv[dd], xv[dd], sx);
      }
#pragma unroll
      for (int dd = 0; dd < 8; ++dd) {
        const float* wd = wp + (((d8 << 3) + dd) << 9);
#pragma unroll
        for (int c = 0; c < 32; ++c) acc[c] = fmaf(wd[c], xv[dd], acc[c]);
      }
    }
#pragma unroll
    for (int c = 0; c < 32; ++c) {
      float dist = fmaf(acc[c], -2.0f, wsq[k0 + c]);
      if (dist < best) { best = dist; bidx = k0 + c; }
    }
  }

  unsigned int ub = __float_as_uint(best);
  ub = (ub & 0x80000000u) ? ~ub : (ub | 0x80000000u);
  sm_key[wv][lane] =
      ((unsigned long long)ub << 32) | (unsigned long long)(unsigned int)bidx;
  if (wv == 0) sm_sx[lane] = sx;
  __syncthreads();

  if (t < 64) {
    unsigned long long k = sm_key[0][t];
#pragma unroll
    for (int wi = 1; wi < 8; ++wi) {
      unsigned long long k2 = sm_key[wi][t];
      k = k2 < k ? k2 : k;
    }
    unsigned int idx = (unsigned int)k;
    sm_idx[t] = idx;
    out_idx[((size_t)pb << 6) + t] = (float)idx;
    unsigned int u = (unsigned int)(k >> 32);
    u = (u & 0x80000000u) ? (u & 0x7FFFFFFFu) : ~u;
    sm_loss[t] = (__uint_as_float(u) + sm_sx[t]) * (1.25f / 4194304.0f);
  }
  __syncthreads();

  float4* dst = (float4*)(out_q + (size_t)pb * 4096);
#pragma unroll
  for (int i = 0; i < 2; ++i) {
    int e4 = i * 512 + t;
    int p2 = e4 >> 4, d4 = e4 & 15;
    unsigned int idx = sm_idx[p2];
    dst[e4] = ((const float4*)(wT + (size_t)idx * DDIM))[d4];
  }

  if (t < 64) {
    float s = sm_loss[t];
#pragma unroll
    for (int off = 32; off > 0; off >>= 1) s += __shfl_down(s, off);
    if (t == 0) atomicAdd(loss_out, s);
  }
}

extern "C" void kernel_launch(void* const* d_in, const int* in_sizes, int n_in,
                              void* d_out, int out_size, void* d_ws, size_t ws_size,
                              hipStream_t stream) {
  const float* x = (const float*)d_in[0];  // (64,32,32,64) fp32
  const float* w = (const float*)d_in[1];  // (64,512) fp32

  float* out_q = (float*)d_out;            // 4194304 floats
  float* out_idx = out_q + 4194304;        // 65536 floats (indices)
  float* loss_out = out_q + 4259840;       // 1 float

  char* ws = (char*)d_ws;
  if (ws_size >= 264192) {
    f16x8* wbp = (f16x8*)(ws);
    float* wT = (float*)(ws + 131072);
    float* wsq = (float*)(ws + 262144);
    vq_prep_m<<<152, 256, 0, stream>>>(w, wbp, wT, wsq, loss_out);
    vq_mfma<<<512, 256, 0, stream>>>(x, wbp, wsq, wT, out_q, out_idx,
                                     loss_out);
  } else {
    float* wT = (float*)(ws);
    float* wsq = (float*)(ws + 131072);
    vq_prep<<<128, 256, 0, stream>>>(w, wT, wsq, loss_out);
    vq_main<<<1024, 512, 0, stream>>>(x, w, wT, wsq, out_q, out_idx,
                                      loss_out);
  }
}

// Round 13
// 92.169 us; speedup vs baseline: 1.7880x; 1.0070x over previous
//
#include <hip/hip_runtime.h>
#include <stdint.h>

// VectorQuantizer on MI355X (gfx950), round 25: R24 + software-pipelined
// wsq. R24 = 92.81us verified (fp16 3-term split, barrier-free global-B
// stream, coalesced wT prep). Remaining audited defect: per-iteration
// wsq[kk] load is issued AFTER the bb(kk+1) prefetches and consumed at the
// iteration END -> the FIFO wait before argmin drains the pipeline every
// iteration (exposed ~200cy L2 latency x 32). Fix: load wsq[kk+1] during
// iteration kk (with the bb prefetches), consume register wq_cur from the
// previous iteration. Rotation static under existing unroll 2. Everything
// else byte-identical to R24. Fragment maps R11-verified.

#define DDIM 64
#define KCODES 512

typedef _Float16 f16x8 __attribute__((ext_vector_type(8)));
typedef float f32x4 __attribute__((ext_vector_type(4)));

// ws layout (bytes): WB @0 (128 chunks x 1KB = 131072), wT @131072 (131072),
//                    wsq @262144 (2048) -> need 264192

__device__ __forceinline__ void split2(float f, _Float16& h1, _Float16& h2) {
  h1 = (_Float16)f;
  float r = f - (float)h1;   // exact (Sterbenz: RN(f) within factor 2 of f)
  h2 = (_Float16)r;          // residual beyond h2 ~ 2^-22 |f|
}

__global__ void vq_prep_m(const float* __restrict__ w,
                          f16x8* __restrict__ wb,    // [128][64] chunks
                          float* __restrict__ wT, float* __restrict__ wsq,
                          float* __restrict__ loss_out) {
  const int b = blockIdx.x, t = threadIdx.x;
  if (b < 16) {
    // ---- w split -> B-fragment chunks, fp16 layout ----
    // chunk G = ctg*4 + h*2 + s (ctg = 16-code tile 0..31, h = k-half,
    // s = split term). Element (G,L) = split s of
    // B[k=quad*8+32h+j][n=ctg*16+col]  (R11 bench-verified fragment map)
    const int c = b * 256 + t;                // 0..4095
    const int ctg = c >> 7;                   // 16-code tile 0..31
    const int h = (c >> 6) & 1;               // k-half
    const int L = c & 63, quad = L >> 4, col = L & 15;
    f16x8 v1, v2;
#pragma unroll
    for (int j = 0; j < 8; ++j) {
      float f = w[(quad * 8 + 32 * h + j) * KCODES + ctg * 16 + col];
      _Float16 h1, h2; split2(f, h1, h2);
      v1[j] = h1; v2[j] = h2;
    }
    const int base = ctg * 4 + h * 2;
    wb[(base + 0) * 64 + L] = v1;
    wb[(base + 1) * 64 + L] = v2;
  } else if (b < 144) {
    // ---- wT transpose (coalesced writes; strided reads L2-absorbed)
    // + loss zero ----
    int g = (b - 16) * 256 + t;               // 0..32767 over K*D
    int k = g >> 6, d = g & 63;
    wT[k * DDIM + d] = w[d * KCODES + k];
    if (g == 0) *loss_out = 0.f;              // d_out is poisoned each launch
  } else {
    // ---- wsq: 4 threads per code, 16 elems each, shfl tree ----
    int i = (b - 144) * 256 + t;              // 0..2047
    int k = i >> 2, p = i & 3;
    float s = 0.f;
#pragma unroll
    for (int dd = 0; dd < 16; ++dd) {
      float tv = w[(p * 16 + dd) * KCODES + k];
      s = fmaf(tv, tv, s);
    }
    s += __shfl_xor(s, 1, 64);
    s += __shfl_xor(s, 2, 64);
    if (p == 0) wsq[k] = s;
  }
}

__global__ __launch_bounds__(256, 2)
void vq_mfma(const float* __restrict__ x_in, const f16x8* __restrict__ wb,
             const float* __restrict__ wsq, const float* __restrict__ wT,
             float* __restrict__ out_q, float* __restrict__ out_idx,
             float* __restrict__ loss_out) {
  __shared__ unsigned long long sm_key[128];
  __shared__ float sm_xsq[128];
  __shared__ unsigned int sm_idx[128];
  __shared__ float sm_loss[128];

  const int t = threadIdx.x, b = blockIdx.x;  // 512 blocks, 128 pts each
  const int wv = t >> 6, L = t & 63, quad = L >> 4, col = L & 15;

  // ---- issue iteration-0 B prefetch + wsq[0] FIRST (latency hides under
  // the x prologue's loads + split VALU) ----
  f16x8 bb[2][4];
#pragma unroll
  for (int j = 0; j < 4; ++j) bb[0][j] = wb[j * 64 + L];
  float wq_cur = wsq[col];

  // ---- load A-fragments straight from x, split2 in-register ----
  // a[as][s][h]; lane holds A[m=col][k=quad*8+32h+j] of point
  // pt = b*128 + (wv*2+as)*16 + col   (R11/R15 bench-verified A layout)
  f16x8 a[2][2][2];
#pragma unroll
  for (int as = 0; as < 2; ++as) {
    const float* xr =
        x_in + ((size_t)b * 128 + (wv * 2 + as) * 16 + col) * DDIM + quad * 8;
    float ssq = 0.f;
#pragma unroll
    for (int h = 0; h < 2; ++h) {
      float4 p0 = *(const float4*)(xr + 32 * h);
      float4 p1 = *(const float4*)(xr + 32 * h + 4);
      float f[8] = {p0.x, p0.y, p0.z, p0.w, p1.x, p1.y, p1.z, p1.w};
      f16x8 v1, v2;
#pragma unroll
      for (int j = 0; j < 8; ++j) {
        ssq = fmaf(f[j], f[j], ssq);
        _Float16 h1, h2; split2(f[j], h1, h2);
        v1[j] = h1; v2[j] = h2;
      }
      a[as][0][h] = v1; a[as][1][h] = v2;
    }
    // combine the 4 quads (lanes col, col+16, col+32, col+48 = same point)
    ssq += __shfl_xor(ssq, 16, 64);
    ssq += __shfl_xor(ssq, 32, 64);
    if (quad == 0) sm_xsq[wv * 32 + as * 16 + col] = ssq;  // fp32-exact
  }

  float best[2][4];
  int bidx[2][4];
#pragma unroll
  for (int as = 0; as < 2; ++as)
#pragma unroll
    for (int r = 0; r < 4; ++r) { best[as][r] = 3.0e38f; bidx[as][r] = 0; }

  // ---- main loop: 32 free-running iterations (kk over 16-code tiles),
  // NO barriers. Iter kk consumes chunks 4kk..4kk+3 from bb[kk&1] and the
  // wq_cur register loaded in iter kk-1; prefetches bb(kk+1) AND
  // wsq(kk+1). FIFO effect: the argmin's wait targets a load issued one
  // full iteration ago -> the 5 newest loads stay in flight across the
  // iteration boundary (no per-iteration drain). unroll 2 -> parity and
  // the wq rotation are static (rule #20).
#pragma unroll 2
  for (int kk = 0; kk < 32; ++kk) {
    const int cur = kk & 1, nxt = cur ^ 1;
    float wq_nxt = 0.f;
    if (kk < 31) {
#pragma unroll
      for (int j = 0; j < 4; ++j)
        bb[nxt][j] = wb[(kk + 1) * 256 + j * 64 + L];
      wq_nxt = wsq[(kk + 1) * 16 + col];     // 2KB L2-hot table
    }

    // 12 MFMA: per as, dual-acc (h=0 -> aA, h=1 -> aB), 3-term fp16 split
    // {x1w1, x1w2, x2w1}; dropped x2w2 ~ 2^-22|x||w|.
    f32x4 aA0 = {0.f, 0.f, 0.f, 0.f}, aB0 = {0.f, 0.f, 0.f, 0.f};
    f32x4 aA1 = {0.f, 0.f, 0.f, 0.f}, aB1 = {0.f, 0.f, 0.f, 0.f};
    {
      f16x8 b0 = bb[cur][0], b1 = bb[cur][1];   // h=0: w1, w2
      aA0 = __builtin_amdgcn_mfma_f32_16x16x32_f16(a[0][0][0], b0, aA0, 0, 0, 0);
      aA1 = __builtin_amdgcn_mfma_f32_16x16x32_f16(a[1][0][0], b0, aA1, 0, 0, 0);
      aA0 = __builtin_amdgcn_mfma_f32_16x16x32_f16(a[0][0][0], b1, aA0, 0, 0, 0);
      aA1 = __builtin_amdgcn_mfma_f32_16x16x32_f16(a[1][0][0], b1, aA1, 0, 0, 0);
      aA0 = __builtin_amdgcn_mfma_f32_16x16x32_f16(a[0][1][0], b0, aA0, 0, 0, 0);
      aA1 = __builtin_amdgcn_mfma_f32_16x16x32_f16(a[1][1][0], b0, aA1, 0, 0, 0);
    }
    {
      f16x8 b2 = bb[cur][2], b3 = bb[cur][3];   // h=1: w1, w2
      aB0 = __builtin_amdgcn_mfma_f32_16x16x32_f16(a[0][0][1], b2, aB0, 0, 0, 0);
      aB1 = __builtin_amdgcn_mfma_f32_16x16x32_f16(a[1][0][1], b2, aB1, 0, 0, 0);
      aB0 = __builtin_amdgcn_mfma_f32_16x16x32_f16(a[0][0][1], b3, aB0, 0, 0, 0);
      aB1 = __builtin_amdgcn_mfma_f32_16x16x32_f16(a[1][0][1], b3, aB1, 0, 0, 0);
      aB0 = __builtin_amdgcn_mfma_f32_16x16x32_f16(a[0][1][1], b2, aB0, 0, 0, 0);
      aB1 = __builtin_amdgcn_mfma_f32_16x16x32_f16(a[1][1][1], b2, aB1, 0, 0, 0);
    }
    f32x4 acc0 = aA0 + aB0;
    f32x4 acc1 = aA1 + aB1;
    // dist + per-lane argmin; C layout: pt = quad*4 + r, code = col
    int code = kk * 16 + col;
#pragma unroll
    for (int r = 0; r < 4; ++r) {
      float d0 = fmaf(acc0[r], -2.0f, wq_cur);
      if (d0 < best[0][r]) { best[0][r] = d0; bidx[0][r] = code; }
      float d1 = fmaf(acc1[r], -2.0f, wq_cur);
      if (d1 < best[1][r]) { best[1][r] = d1; bidx[1][r] = code; }
    }
    wq_cur = wq_nxt;
  }

  // ---- cross-lane reduce over the 16 cols; idx in low bits -> lowest idx ----
#pragma unroll
  for (int as = 0; as < 2; ++as) {
#pragma unroll
    for (int r = 0; r < 4; ++r) {
      unsigned int ub = __float_as_uint(best[as][r]);
      ub = (ub & 0x80000000u) ? ~ub : (ub | 0x80000000u);
      unsigned long long key = ((unsigned long long)ub << 32) |
                               (unsigned long long)(unsigned int)bidx[as][r];
#pragma unroll
      for (int off = 1; off < 16; off <<= 1) {
        unsigned long long o = __shfl_xor(key, off, 64);
        key = o < key ? o : key;
      }
      if (col == 0)
        sm_key[wv * 32 + as * 16 + quad * 4 + r] = key;
    }
  }
  __syncthreads();

  if (t < 128) {
    unsigned long long k = sm_key[t];
    unsigned int idx = (unsigned int)k;
    sm_idx[t] = idx;
    out_idx[(size_t)b * 128 + t] = (float)idx;
    unsigned int u = (unsigned int)(k >> 32);
    u = (u & 0x80000000u) ? (u & 0x7FFFFFFFu) : ~u;
    // ||x-q||^2 = ||x||^2 + (||q||^2 - 2 x.q), pre-scaled by 1.25/(N*D)
    sm_loss[t] = (__uint_as_float(u) + sm_xsq[t]) * (1.25f / 4194304.0f);
  }
  __syncthreads();

  // ---- fused epilogue: gather code rows, coalesced 128x64 out tile ----
  float4* dst = (float4*)(out_q + (size_t)b * 8192);
#pragma unroll
  for (int i = 0; i < 8; ++i) {
    int e4 = i * 256 + t;
    int p2 = e4 >> 4, d4 = e4 & 15;
    unsigned int idx = sm_idx[p2];                            // LDS broadcast
    dst[e4] = ((const float4*)(wT + (size_t)idx * DDIM))[d4]; // L2-hot
  }

  if (t < 64) {
    float s = sm_loss[t] + sm_loss[t + 64];
#pragma unroll
    for (int off = 32; off > 0; off >>= 1) s += __shfl_down(s, off);
    if (t == 0) atomicAdd(loss_out, s);       // 512 adds total
  }
}

// ---------------- fallback (R9 kernels, proven) ----------------

__global__ void vq_prep(const float* __restrict__ w, float* __restrict__ wT,
                        float* __restrict__ wsq, float* __restrict__ loss_out) {
  int g = blockIdx.x * 256 + threadIdx.x;
  int d = g >> 9, k = g & 511;
  wT[k * DDIM + d] = w[g];
  if (g < KCODES) {
    float s = 0.f;
    for (int dd = 0; dd < DDIM; ++dd) {
      float t = w[dd * KCODES + g];
      s = fmaf(t, t, s);
    }
    wsq[g] = s;
  }
  if (g == 0) *loss_out = 0.f;
}

__global__ __launch_bounds__(512, 8)
void vq_main(const float* __restrict__ x_in, const float* __restrict__ w,
             const float* __restrict__ wT, const float* __restrict__ wsq,
             float* __restrict__ out_q, float* __restrict__ out_idx,
             float* __restrict__ loss_out) {
  __shared__ float xs[DDIM][65];
  __shared__ unsigned long long sm_key[8][64];
  __shared__ unsigned int sm_idx[64];
  __shared__ float sm_sx[64];
  __shared__ float sm_loss[64];

  const int t = threadIdx.x;
  const int pb = blockIdx.x;
  const int wv = __builtin_amdgcn_readfirstlane(t >> 6);
  const int lane = t & 63;

  {
    const float4* src = (const float4*)(x_in + (size_t)pb * 4096);
#pragma unroll
    for (int i = 0; i < 2; ++i) {
      int e4 = i * 512 + t;
      float4 v = src[e4];
      int e = e4 << 2;
      int pt = e >> 6, d = e & 63;
      xs[d][pt] = v.x; xs[d + 1][pt] = v.y;
      xs[d + 2][pt] = v.z; xs[d + 3][pt] = v.w;
    }
  }
  __syncthreads();

  const int kbase = wv << 6;
  float best = 3.0e38f;
  int bidx = 0;
  float sx = 0.f;

#pragma unroll 1
  for (int kb = 0; kb < 2; ++kb) {
    const int k0 = kbase + (kb << 5);
    const float* wp = w + k0;
    float acc[32];
#pragma unroll
    for (int c = 0; c < 32; ++c) acc[c] = 0.f;
#pragma unroll 1
    for (int d8 = 0; d8 < 8; ++d8) {
      float xv[8];
#pragma unroll
      for (int dd = 0; dd < 8; ++dd) xv[dd] = xs[(d8 << 3) + dd][lane];
      if (wv == 0 && kb == 0) {
#pragma unroll
        for (int dd = 0; dd < 8; ++dd) sx = fmaf(xv[dd], xv[dd], sx);
      }
#pragma unroll
      for (int dd = 0; dd < 8; ++dd) {
        const float* wd = wp + (((d8 << 3) + dd) << 9);
#pragma unroll
        for (int c = 0; c < 32; ++c) acc[c] = fmaf(wd[c], xv[dd], acc[c]);
      }
    }
#pragma unroll
    for (int c = 0; c < 32; ++c) {
      float dist = fmaf(acc[c], -2.0f, wsq[k0 + c]);
      if (dist < best) { best = dist; bidx = k0 + c; }
    }
  }

  unsigned int ub = __float_as_uint(best);
  ub = (ub & 0x80000000u) ? ~ub : (ub | 0x80000000u);
  sm_key[wv][lane] =
      ((unsigned long long)ub << 32) | (unsigned long long)(unsigned int)bidx;
  if (wv == 0) sm_sx[lane] = sx;
  __syncthreads();

  if (t < 64) {
    unsigned long long k = sm_key[0][t];
#pragma unroll
    for (int wi = 1; wi < 8; ++wi) {
      unsigned long long k2 = sm_key[wi][t];
      k = k2 < k ? k2 : k;
    }
    unsigned int idx = (unsigned int)k;
    sm_idx[t] = idx;
    out_idx[((size_t)pb << 6) + t] = (float)idx;
    unsigned int u = (unsigned int)(k >> 32);
    u = (u & 0x80000000u) ? (u & 0x7FFFFFFFu) : ~u;
    sm_loss[t] = (__uint_as_float(u) + sm_sx[t]) * (1.25f / 4194304.0f);
  }
  __syncthreads();

  float4* dst = (float4*)(out_q + (size_t)pb * 4096);
#pragma unroll
  for (int i = 0; i < 2; ++i) {
    int e4 = i * 512 + t;
    int p2 = e4 >> 4, d4 = e4 & 15;
    unsigned int idx = sm_idx[p2];
    dst[e4] = ((const float4*)(wT + (size_t)idx * DDIM))[d4];
  }

  if (t < 64) {
    float s = sm_loss[t];
#pragma unroll
    for (int off = 32; off > 0; off >>= 1) s += __shfl_down(s, off);
    if (t == 0) atomicAdd(loss_out, s);
  }
}

extern "C" void kernel_launch(void* const* d_in, const int* in_sizes, int n_in,
                              void* d_out, int out_size, void* d_ws, size_t ws_size,
                              hipStream_t stream) {
  const float* x = (const float*)d_in[0];  // (64,32,32,64) fp32
  const float* w = (const float*)d_in[1];  // (64,512) fp32

  float* out_q = (float*)d_out;            // 4194304 floats
  float* out_idx = out_q + 4194304;        // 65536 floats (indices)
  float* loss_out = out_q + 4259840;       // 1 float

  char* ws = (char*)d_ws;
  if (ws_size >= 264192) {
    f16x8* wbp = (f16x8*)(ws);
    float* wT = (float*)(ws + 131072);
    float* wsq = (float*)(ws + 262144);
    vq_prep_m<<<152, 256, 0, stream>>>(w, wbp, wT, wsq, loss_out);
    vq_mfma<<<512, 256, 0, stream>>>(x, wbp, wsq, wT, out_q, out_idx,
                                     loss_out);
  } else {
    float* wT = (float*)(ws);
    float* wsq = (float*)(ws + 131072);
    vq_prep<<<128, 256, 0, stream>>>(w, wT, wsq, loss_out);
    vq_main<<<1024, 512, 0, stream>>>(x, w, wT, wsq, out_q, out_idx,
                                      loss_out);
  }
}